// Round 10
// baseline (185.874 us; speedup 1.0000x reference)
//
#include <hip/hip_runtime.h>

#define D 64  // D_IN == D_OUT == 64

typedef unsigned short ushort_t;
typedef __attribute__((ext_vector_type(8))) short bf16x8;
typedef __attribute__((ext_vector_type(4))) float f32x4;

__device__ __forceinline__ void fma4(float4& c, float a, const float4& b) {
  c.x = fmaf(a, b.x, c.x);
  c.y = fmaf(a, b.y, c.y);
  c.z = fmaf(a, b.z, c.z);
  c.w = fmaf(a, b.w, c.w);
}

__device__ __forceinline__ unsigned short f2bf(float f) {  // RNE pack
  unsigned u = __float_as_uint(f);
  return (unsigned short)((u + 0x7FFFu + ((u >> 16) & 1u)) >> 16);
}
__device__ __forceinline__ float bf2f(unsigned short h) {
  return __uint_as_float((unsigned)h << 16);
}
__device__ __forceinline__ unsigned pk2(float a, float b) {
  return (unsigned)f2bf(a) | ((unsigned)f2bf(b) << 16);
}

__device__ __forceinline__ bf16x8 pack_bf8(float4 v0, float4 v1) {
  bf16x8 r;
  r[0] = (short)f2bf(v0.x); r[1] = (short)f2bf(v0.y);
  r[2] = (short)f2bf(v0.z); r[3] = (short)f2bf(v0.w);
  r[4] = (short)f2bf(v1.x); r[5] = (short)f2bf(v1.y);
  r[6] = (short)f2bf(v1.z); r[7] = (short)f2bf(v1.w);
  return r;
}

// ---------------- K1: prep = W transpose (blocks 0..R) || zero deg ----------------
__global__ void prep(const float* __restrict__ weight, const float* __restrict__ loopw,
                     ushort_t* __restrict__ Wt, int* __restrict__ deg, int R, int N) {
  if ((int)blockIdx.x <= R) {
    const int m = blockIdx.x;
    const float* W = (m < R) ? weight + (size_t)m * D * D : loopw;
    ushort_t* o = Wt + (size_t)m * D * D;
    for (int i = threadIdx.x; i < 1024; i += 256) {
      float4 v = ((const float4*)W)[i];
      int k = i >> 4;
      int c = (i & 15) * 4;
      o[(c + 0) * D + k] = f2bf(v.x);
      o[(c + 1) * D + k] = f2bf(v.y);
      o[(c + 2) * D + k] = f2bf(v.z);
      o[(c + 3) * D + k] = f2bf(v.w);
    }
  } else {
    int i = (blockIdx.x - (R + 1)) * 256 + threadIdx.x;
    if (i < N) deg[i] = 0;
  }
}

// ---------------- K2: proj (MFMA, LDS-free, tiled layout) || hist_rank ----------------
// proj device body. NM>0: compile-time matrix count (unrolled); NM==0: runtime loop.
template <int NM>
__device__ __forceinline__ void proj_body(const float* __restrict__ feat,
                                          const ushort_t* __restrict__ Wt,
                                          ushort_t* __restrict__ proj,
                                          float* __restrict__ out, int N, int R,
                                          int blk) {
  const int t = threadIdx.x;
  const int lane = t & 63;
  const int wid = t >> 6;
  const int node = blk * 64 + wid * 16 + (lane & 15);
  const int g = lane >> 4;
  const int kb = g * 8;

  bf16x8 b[2];
#pragma unroll
  for (int kh = 0; kh < 2; ++kh) {
    float4 v0 = make_float4(0.f, 0.f, 0.f, 0.f);
    float4 v1 = v0;
    if (node < N) {
      const float* p = feat + (size_t)node * D + kh * 32 + kb;
      v0 = *(const float4*)p;
      v1 = *(const float4*)(p + 4);
    }
    b[kh] = pack_bf8(v0, v1);
  }

  const int nm = NM > 0 ? NM : (R + 1);
#pragma unroll 2
  for (int m = 0; m < nm; ++m) {
    const ushort_t* wt = Wt + (size_t)m * D * D;

    f32x4 acc[4];
#pragma unroll
    for (int ct = 0; ct < 4; ++ct) {
      const ushort_t* wr = wt + (size_t)(16 * ct + (lane & 15)) * D + kb;
      bf16x8 a0 = *(const bf16x8*)wr;
      bf16x8 a1 = *(const bf16x8*)(wr + 32);
      acc[ct] = (f32x4){0.f, 0.f, 0.f, 0.f};
      acc[ct] = __builtin_amdgcn_mfma_f32_16x16x32_bf16(a0, b[0], acc[ct], 0, 0, 0);
      acc[ct] = __builtin_amdgcn_mfma_f32_16x16x32_bf16(a1, b[1], acc[ct], 0, 0, 0);
    }

    if (node < N) {
      if (m < R) {
        // Tiled layout: storage 16g+4ct+r <-> actual col 16ct+4g+r.
        ushort_t* op = proj + ((size_t)m * N + node) * D + 16 * g;
        uint4 w0, w1;
        w0.x = pk2(acc[0][0], acc[0][1]); w0.y = pk2(acc[0][2], acc[0][3]);
        w0.z = pk2(acc[1][0], acc[1][1]); w0.w = pk2(acc[1][2], acc[1][3]);
        w1.x = pk2(acc[2][0], acc[2][1]); w1.y = pk2(acc[2][2], acc[2][3]);
        w1.z = pk2(acc[3][0], acc[3][1]); w1.w = pk2(acc[3][2], acc[3][3]);
        *(uint4*)(op) = w0;
        *(uint4*)(op + 8) = w1;
      } else {
        float* op = out + (size_t)node * D + 4 * g;
#pragma unroll
        for (int ct = 0; ct < 4; ++ct) {
          float4 v;
          v.x = acc[ct][0]; v.y = acc[ct][1]; v.z = acc[ct][2]; v.w = acc[ct][3];
          *(float4*)(op + 16 * ct) = v;
        }
      }
    }
  }
}

__device__ __forceinline__ void hist_body(const int* __restrict__ edst,
                                          int* __restrict__ deg,
                                          int* __restrict__ rank, int E, int hblk) {
  const int e = (hblk * 256 + (int)threadIdx.x) * 2;
  if (e + 1 < E) {
    int2 d = *(const int2*)(edst + e);
    int r0 = atomicAdd(&deg[d.x], 1);
    int r1 = atomicAdd(&deg[d.y], 1);
    *(int2*)(rank + e) = make_int2(r0, r1);
  } else if (e < E) {
    rank[e] = atomicAdd(&deg[edst[e]], 1);
  }
}

// Blocks [0,PB): proj (R==8 fast path unrolled). Blocks [PB,PB+HB): hist_rank.
__global__ __launch_bounds__(256) void proj_hist(const float* __restrict__ feat,
                                                 const ushort_t* __restrict__ Wt,
                                                 ushort_t* __restrict__ proj,
                                                 float* __restrict__ out,
                                                 const int* __restrict__ edst,
                                                 int* __restrict__ deg,
                                                 int* __restrict__ rank,
                                                 int N, int E, int R, int PB) {
  if ((int)blockIdx.x < PB) {
    if (R == 8)
      proj_body<9>(feat, Wt, proj, out, N, R, blockIdx.x);
    else
      proj_body<0>(feat, Wt, proj, out, N, R, blockIdx.x);
  } else {
    hist_body(edst, deg, rank, E, blockIdx.x - PB);
  }
}

// ---------------- K3: single-launch exclusive scan ----------------
// One block, 1024 threads, C = ceil(N/1024) contiguous elems per thread.
__global__ __launch_bounds__(1024) void scan_all(const int* __restrict__ deg,
                                                 int* __restrict__ off, int N) {
  __shared__ int sh[1024];
  const int t = threadIdx.x;
  const int C = (N + 1023) >> 10;
  const int s = t * C;
  const int e = min(N, s + C);
  int sum = 0;
  for (int i = s; i < e; ++i) sum += deg[i];
  sh[t] = sum;
  __syncthreads();
#pragma unroll
  for (int d = 1; d < 1024; d <<= 1) {
    int u = (t >= d) ? sh[t - d] : 0;
    __syncthreads();
    sh[t] += u;
    __syncthreads();
  }
  int base = sh[t] - sum;
  if (t == 1023) off[N] = sh[1023];
  for (int i = s; i < e; ++i) {
    int v = deg[i];
    off[i] = base;
    base += v;
  }
}

// ---------------- K4: scatter payloads (pos = off[dst] + rank, no atomics) ----------------
__global__ void scatter_pos(const int* __restrict__ esrc, const int* __restrict__ edst,
                            const int* __restrict__ etype, const float* __restrict__ att,
                            const int* __restrict__ off, const int* __restrict__ rank,
                            int2* __restrict__ payload, int E) {
  const int e = (blockIdx.x * 256 + threadIdx.x) * 4;
  if (e + 3 < E) {
    int4 s  = *(const int4*)(esrc + e);
    int4 d  = *(const int4*)(edst + e);
    int4 ty = *(const int4*)(etype + e);
    float4 a = *(const float4*)(att + e);
    int4 rk = *(const int4*)(rank + e);
    payload[off[d.x] + rk.x] = make_int2(s.x | (ty.x << 24), __float_as_int(a.x));
    payload[off[d.y] + rk.y] = make_int2(s.y | (ty.y << 24), __float_as_int(a.y));
    payload[off[d.z] + rk.z] = make_int2(s.z | (ty.z << 24), __float_as_int(a.z));
    payload[off[d.w] + rk.w] = make_int2(s.w | (ty.w << 24), __float_as_int(a.w));
  } else {
    for (int i = e; i < E; ++i)
      payload[off[edst[i]] + rank[i]] =
          make_int2(esrc[i] | (etype[i] << 24), __float_as_int(att[i]));
  }
}

// ---------------- K5: node gather (tiled proj layout) ----------------
__global__ __launch_bounds__(256, 8) void node_gather(const int* __restrict__ off,
                                                      const int2* __restrict__ payload,
                                                      const ushort_t* __restrict__ proj,
                                                      const float* __restrict__ hbias,
                                                      float* __restrict__ out, int N) {
  const int n = (blockIdx.x * 256 + threadIdx.x) >> 6;
  if (n >= N) return;
  const int lane = threadIdx.x & 63;
  const int sub = lane >> 4;
  const int q = lane & 15;
  const int ac0 = 16 * (q & 3) + 4 * (q >> 2);   // actual col base for chunk q

  const int s0 = off[n], s1 = off[n + 1];
  float4 acc = make_float4(0.f, 0.f, 0.f, 0.f);
  float sa = 0.f;
  for (int e = s0 + sub; e < s1; e += 4) {
    const int2 pe = payload[e];
    const float a = __int_as_float(pe.y);
    const int src = pe.x & 0x00FFFFFF;
    const int r = ((unsigned)pe.x) >> 24;
    const ushort4 p = *(const ushort4*)(proj + ((size_t)r * N + src) * D + q * 4);
    acc.x = fmaf(a, bf2f(p.x), acc.x);
    acc.y = fmaf(a, bf2f(p.y), acc.y);
    acc.z = fmaf(a, bf2f(p.z), acc.z);
    acc.w = fmaf(a, bf2f(p.w), acc.w);
    sa += a;
  }
#pragma unroll
  for (int m = 16; m < 64; m <<= 1) {
    acc.x += __shfl_xor(acc.x, m);
    acc.y += __shfl_xor(acc.y, m);
    acc.z += __shfl_xor(acc.z, m);
    acc.w += __shfl_xor(acc.w, m);
    sa += __shfl_xor(sa, m);
  }
  if (sub == 0) {
    const float4 hb = *(const float4*)(hbias + ac0);
    float* op = out + (size_t)n * D + ac0;
    float4 cur = *(float4*)op;      // self-loop already there (canonical layout)
    cur.x += acc.x + sa * hb.x;
    cur.y += acc.y + sa * hb.y;
    cur.z += acc.z + sa * hb.z;
    cur.w += acc.w + sa * hb.w;
    *(float4*)op = cur;
  }
}

// ---------------- fallback path (small ws): fp32 tile GEMM + atomic scatter ----------------
__global__ __launch_bounds__(256, 3) void proj_single(const float* __restrict__ feat,
                                                      const float* __restrict__ W,
                                                      float* __restrict__ outp, int N) {
  __shared__ float sW[64 * 64];
  __shared__ float sF[64 * 132];
  const int t = threadIdx.x;
  const int tileBase = blockIdx.x * 128;

  {
    const float4* Wv = (const float4*)W;
    float4* sWv = (float4*)sW;
    for (int k = t; k < 1024; k += 256) sWv[k] = Wv[k];
  }
  {
    const int row = t >> 1, half = t & 1;
    const int gr = tileBase + row;
    if (gr < N) {
      const float4* src = (const float4*)(feat + (size_t)gr * D + half * 32);
#pragma unroll
      for (int k = 0; k < 8; ++k) {
        float4 v = src[k];
        int i0 = half * 32 + k * 4;
        sF[(i0 + 0) * 132 + row] = v.x;
        sF[(i0 + 1) * 132 + row] = v.y;
        sF[(i0 + 2) * 132 + row] = v.z;
        sF[(i0 + 3) * 132 + row] = v.w;
      }
    } else {
#pragma unroll
      for (int k = 0; k < 8; ++k) {
        int i0 = half * 32 + k * 4;
        sF[(i0 + 0) * 132 + row] = 0.f;
        sF[(i0 + 1) * 132 + row] = 0.f;
        sF[(i0 + 2) * 132 + row] = 0.f;
        sF[(i0 + 3) * 132 + row] = 0.f;
      }
    }
  }
  __syncthreads();

  const int c0 = (t & 15) * 4;
  const int r0 = (t >> 4) * 8;
  float4 acc[8];
#pragma unroll
  for (int rr = 0; rr < 8; ++rr) acc[rr] = make_float4(0.f, 0.f, 0.f, 0.f);

#pragma unroll 8
  for (int i = 0; i < 64; ++i) {
    float4 w  = *(const float4*)&sW[i * 64 + c0];
    float4 a0 = *(const float4*)&sF[i * 132 + r0];
    float4 a1 = *(const float4*)&sF[i * 132 + r0 + 4];
    fma4(acc[0], a0.x, w); fma4(acc[1], a0.y, w);
    fma4(acc[2], a0.z, w); fma4(acc[3], a0.w, w);
    fma4(acc[4], a1.x, w); fma4(acc[5], a1.y, w);
    fma4(acc[6], a1.z, w); fma4(acc[7], a1.w, w);
  }

#pragma unroll
  for (int rr = 0; rr < 8; ++rr) {
    int gn = tileBase + r0 + rr;
    if (gn < N) *(float4*)(outp + (size_t)gn * D + c0) = acc[rr];
  }
}

__global__ __launch_bounds__(256, 8) void edge_scatter(const int* __restrict__ esrc,
                                                       const int* __restrict__ edst,
                                                       const int* __restrict__ etype,
                                                       const float* __restrict__ att,
                                                       const float* __restrict__ proj,
                                                       const float* __restrict__ hbias,
                                                       float* __restrict__ out,
                                                       int E, int N, int relFilter) {
  const int t = blockIdx.x * 256 + threadIdx.x;
  const int wave = t >> 6;
  const int lane = threadIdx.x & 63;
  const int sub = lane >> 4;
  const int q = lane & 15;
  const long e = (long)wave * 4 + sub;
  if (e >= E) return;
  const int r = etype[e];
  if (relFilter >= 0 && r != relFilter) return;
  const int s = esrc[e];
  const int dn = edst[e];
  const float a = att[e];
  const size_t base = (relFilter >= 0) ? (size_t)s * D : ((size_t)r * N + s) * D;
  const float4 hb = ((const float4*)hbias)[q];
  const float4 p = *(const float4*)(proj + base + q * 4);
  float* op = out + (size_t)dn * D + q * 4;
  unsafeAtomicAdd(op + 0, (p.x + hb.x) * a);
  unsafeAtomicAdd(op + 1, (p.y + hb.y) * a);
  unsafeAtomicAdd(op + 2, (p.z + hb.z) * a);
  unsafeAtomicAdd(op + 3, (p.w + hb.w) * a);
}

extern "C" void kernel_launch(void* const* d_in, const int* in_sizes, int n_in,
                              void* d_out, int out_size, void* d_ws, size_t ws_size,
                              hipStream_t stream) {
  const float* feat   = (const float*)d_in[0];
  const int* esrc     = (const int*)d_in[1];
  const int* edst     = (const int*)d_in[2];
  const int* etype    = (const int*)d_in[3];
  const float* att    = (const float*)d_in[4];
  const float* weight = (const float*)d_in[5];
  const float* hbias  = (const float*)d_in[6];
  const float* loopw  = (const float*)d_in[7];
  float* out = (float*)d_out;

  const int N = in_sizes[0] / D;          // 50000
  const int E = in_sizes[1];              // 800000
  const int R = in_sizes[5] / (D * D);    // 8

  const int Npad = (N + 3) & ~3;

  // Fast-path workspace layout: Wt | proj(bf16) | deg | off | rank | payload
  const size_t wtBytes   = (size_t)(R + 1) * D * D * 2;
  const size_t projBytes = (size_t)R * N * D * 2;
  const size_t intCount  = (size_t)Npad + (size_t)(N + 1) + (size_t)E;
  const size_t payOff    = (wtBytes + projBytes + intCount * 4 + 7) & ~(size_t)7;
  const size_t needSorted = payOff + (size_t)E * 8;

  const int PB = (N + 63) / 64;                       // proj blocks (64 nodes each)
  const int HB = ((E + 1) / 2 + 255) / 256;           // hist blocks (512 edges each)
  const int equadBlocks = ((E + 3) / 4 + 255) / 256;

  if (ws_size >= needSorted) {
    ushort_t* Wt   = (ushort_t*)d_ws;
    ushort_t* proj = (ushort_t*)((char*)d_ws + wtBytes);
    int* deg    = (int*)((char*)d_ws + wtBytes + projBytes);  // Npad ints
    int* off    = deg + Npad;                                 // N+1
    int* rank   = off + (N + 1);                              // E
    int2* payload = (int2*)((char*)d_ws + payOff);            // E

    prep<<<(R + 1) + (N + 255) / 256, 256, 0, stream>>>(weight, loopw, Wt, deg, R, N);
    proj_hist<<<PB + HB, 256, 0, stream>>>(feat, Wt, proj, out, edst, deg, rank,
                                           N, E, R, PB);
    scan_all<<<1, 1024, 0, stream>>>(deg, off, N);
    scatter_pos<<<equadBlocks, 256, 0, stream>>>(esrc, edst, etype, att, off, rank,
                                                 payload, E);
    node_gather<<<(N + 3) / 4, 256, 0, stream>>>(off, payload, proj, hbias, out, N);
  } else {
    // Minimal-scratch fallback: needs N*D floats.
    const int tilesN = (N + 127) / 128;
    const int eblocks16 = (E + 15) / 16;
    proj_single<<<tilesN, 256, 0, stream>>>(feat, loopw, out, N);
    for (int r = 0; r < R; ++r) {
      proj_single<<<tilesN, 256, 0, stream>>>(feat, weight + (size_t)r * D * D,
                                              (float*)d_ws, N);
      edge_scatter<<<eblocks16, 256, 0, stream>>>(esrc, edst, etype, att, (float*)d_ws,
                                                  hbias, out, E, N, r);
    }
  }
}

// Round 11
// 119.065 us; speedup vs baseline: 1.5611x; 1.5611x over previous
//
#include <hip/hip_runtime.h>

#define D 64  // D_IN == D_OUT == 64

typedef unsigned short ushort_t;
typedef __attribute__((ext_vector_type(8))) short bf16x8;
typedef __attribute__((ext_vector_type(4))) float f32x4;

__device__ __forceinline__ void fma4(float4& c, float a, const float4& b) {
  c.x = fmaf(a, b.x, c.x);
  c.y = fmaf(a, b.y, c.y);
  c.z = fmaf(a, b.z, c.z);
  c.w = fmaf(a, b.w, c.w);
}

__device__ __forceinline__ unsigned short f2bf(float f) {  // RNE pack
  unsigned u = __float_as_uint(f);
  return (unsigned short)((u + 0x7FFFu + ((u >> 16) & 1u)) >> 16);
}
__device__ __forceinline__ float bf2f(unsigned short h) {
  return __uint_as_float((unsigned)h << 16);
}
__device__ __forceinline__ unsigned pk2(float a, float b) {
  return (unsigned)f2bf(a) | ((unsigned)f2bf(b) << 16);
}

__device__ __forceinline__ bf16x8 pack_bf8(float4 v0, float4 v1) {
  bf16x8 r;
  r[0] = (short)f2bf(v0.x); r[1] = (short)f2bf(v0.y);
  r[2] = (short)f2bf(v0.z); r[3] = (short)f2bf(v0.w);
  r[4] = (short)f2bf(v1.x); r[5] = (short)f2bf(v1.y);
  r[6] = (short)f2bf(v1.z); r[7] = (short)f2bf(v1.w);
  return r;
}

// ---------------- K1: prep = W transpose (blocks 0..R) || zero deg ----------------
__global__ void prep(const float* __restrict__ weight, const float* __restrict__ loopw,
                     ushort_t* __restrict__ Wt, int* __restrict__ deg, int R, int N) {
  if ((int)blockIdx.x <= R) {
    const int m = blockIdx.x;
    const float* W = (m < R) ? weight + (size_t)m * D * D : loopw;
    ushort_t* o = Wt + (size_t)m * D * D;
    for (int i = threadIdx.x; i < 1024; i += 256) {
      float4 v = ((const float4*)W)[i];
      int k = i >> 4;
      int c = (i & 15) * 4;
      o[(c + 0) * D + k] = f2bf(v.x);
      o[(c + 1) * D + k] = f2bf(v.y);
      o[(c + 2) * D + k] = f2bf(v.z);
      o[(c + 3) * D + k] = f2bf(v.w);
    }
  } else {
    int i = (blockIdx.x - (R + 1)) * 256 + threadIdx.x;
    if (i < N) deg[i] = 0;
  }
}

// ---------------- K2: proj (MFMA, LDS-free, tiled layout) || hist_rank ----------------
template <int NM>
__device__ __forceinline__ void proj_body(const float* __restrict__ feat,
                                          const ushort_t* __restrict__ Wt,
                                          ushort_t* __restrict__ proj,
                                          float* __restrict__ out, int N, int R,
                                          int blk) {
  const int t = threadIdx.x;
  const int lane = t & 63;
  const int wid = t >> 6;
  const int node = blk * 64 + wid * 16 + (lane & 15);
  const int g = lane >> 4;
  const int kb = g * 8;

  bf16x8 b[2];
#pragma unroll
  for (int kh = 0; kh < 2; ++kh) {
    float4 v0 = make_float4(0.f, 0.f, 0.f, 0.f);
    float4 v1 = v0;
    if (node < N) {
      const float* p = feat + (size_t)node * D + kh * 32 + kb;
      v0 = *(const float4*)p;
      v1 = *(const float4*)(p + 4);
    }
    b[kh] = pack_bf8(v0, v1);
  }

  const int nm = NM > 0 ? NM : (R + 1);
#pragma unroll 2
  for (int m = 0; m < nm; ++m) {
    const ushort_t* wt = Wt + (size_t)m * D * D;

    f32x4 acc[4];
#pragma unroll
    for (int ct = 0; ct < 4; ++ct) {
      const ushort_t* wr = wt + (size_t)(16 * ct + (lane & 15)) * D + kb;
      bf16x8 a0 = *(const bf16x8*)wr;
      bf16x8 a1 = *(const bf16x8*)(wr + 32);
      acc[ct] = (f32x4){0.f, 0.f, 0.f, 0.f};
      acc[ct] = __builtin_amdgcn_mfma_f32_16x16x32_bf16(a0, b[0], acc[ct], 0, 0, 0);
      acc[ct] = __builtin_amdgcn_mfma_f32_16x16x32_bf16(a1, b[1], acc[ct], 0, 0, 0);
    }

    if (node < N) {
      if (m < R) {
        // Tiled layout: storage 16g+4ct+r <-> actual col 16ct+4g+r.
        ushort_t* op = proj + ((size_t)m * N + node) * D + 16 * g;
        uint4 w0, w1;
        w0.x = pk2(acc[0][0], acc[0][1]); w0.y = pk2(acc[0][2], acc[0][3]);
        w0.z = pk2(acc[1][0], acc[1][1]); w0.w = pk2(acc[1][2], acc[1][3]);
        w1.x = pk2(acc[2][0], acc[2][1]); w1.y = pk2(acc[2][2], acc[2][3]);
        w1.z = pk2(acc[3][0], acc[3][1]); w1.w = pk2(acc[3][2], acc[3][3]);
        *(uint4*)(op) = w0;
        *(uint4*)(op + 8) = w1;
      } else {
        float* op = out + (size_t)node * D + 4 * g;
#pragma unroll
        for (int ct = 0; ct < 4; ++ct) {
          float4 v;
          v.x = acc[ct][0]; v.y = acc[ct][1]; v.z = acc[ct][2]; v.w = acc[ct][3];
          *(float4*)(op + 16 * ct) = v;
        }
      }
    }
  }
}

__device__ __forceinline__ void hist_body(const int* __restrict__ edst,
                                          int* __restrict__ deg,
                                          int* __restrict__ rank, int E, int hblk) {
  const int e = (hblk * 256 + (int)threadIdx.x) * 2;
  if (e + 1 < E) {
    int2 d = *(const int2*)(edst + e);
    int r0 = atomicAdd(&deg[d.x], 1);
    int r1 = atomicAdd(&deg[d.y], 1);
    *(int2*)(rank + e) = make_int2(r0, r1);
  } else if (e < E) {
    rank[e] = atomicAdd(&deg[edst[e]], 1);
  }
}

// Blocks [0,PB): proj (R==8 fast path unrolled). Blocks [PB,PB+HB): hist_rank.
__global__ __launch_bounds__(256) void proj_hist(const float* __restrict__ feat,
                                                 const ushort_t* __restrict__ Wt,
                                                 ushort_t* __restrict__ proj,
                                                 float* __restrict__ out,
                                                 const int* __restrict__ edst,
                                                 int* __restrict__ deg,
                                                 int* __restrict__ rank,
                                                 int N, int E, int R, int PB) {
  if ((int)blockIdx.x < PB) {
    if (R == 8)
      proj_body<9>(feat, Wt, proj, out, N, R, blockIdx.x);
    else
      proj_body<0>(feat, Wt, proj, out, N, R, blockIdx.x);
  } else {
    hist_body(edst, deg, rank, E, blockIdx.x - PB);
  }
}

// ---------------- K3a/b/c: two-level exclusive scan (multi-block, coalesced) ----------------
__global__ __launch_bounds__(256) void scan_partial(const int* __restrict__ deg,
                                                    int* __restrict__ bsum, int N) {
  const int t = threadIdx.x;
  const int base = blockIdx.x * 1024 + t * 4;
  int s = 0;
  if (base + 3 < N) {
    int4 v = *(const int4*)(deg + base);
    s = v.x + v.y + v.z + v.w;
  } else {
#pragma unroll
    for (int k = 0; k < 4; ++k) if (base + k < N) s += deg[base + k];
  }
  __shared__ int red[4];
#pragma unroll
  for (int m = 1; m < 64; m <<= 1) s += __shfl_xor(s, m);
  if ((t & 63) == 0) red[t >> 6] = s;
  __syncthreads();
  if (t == 0) bsum[blockIdx.x] = red[0] + red[1] + red[2] + red[3];
}

__global__ __launch_bounds__(256) void scan_bsum(const int* __restrict__ bsum,
                                                 int* __restrict__ boff,
                                                 int* __restrict__ off, int nb, int N) {
  __shared__ int s[256];
  __shared__ int carry_s;
  const int t = threadIdx.x;
  if (t == 0) carry_s = 0;
  __syncthreads();
  for (int base = 0; base < nb; base += 256) {
    int i = base + t;
    int v = (i < nb) ? bsum[i] : 0;
    s[t] = v;
    __syncthreads();
#pragma unroll
    for (int d = 1; d < 256; d <<= 1) {
      int u = (t >= d) ? s[t - d] : 0;
      __syncthreads();
      s[t] += u;
      __syncthreads();
    }
    int c = carry_s;
    if (i < nb) boff[i] = s[t] - v + c;
    __syncthreads();
    if (t == 0) carry_s = c + s[255];
    __syncthreads();
  }
  if (t == 0) off[N] = carry_s;
}

__global__ __launch_bounds__(256) void scan_apply(const int* __restrict__ deg,
                                                  const int* __restrict__ boff,
                                                  int* __restrict__ off, int N) {
  const int t = threadIdx.x;
  const int base = blockIdx.x * 1024 + t * 4;
  int v0 = 0, v1 = 0, v2 = 0, v3 = 0;
  if (base + 3 < N) {
    int4 v = *(const int4*)(deg + base);
    v0 = v.x; v1 = v.y; v2 = v.z; v3 = v.w;
  } else {
    if (base + 0 < N) v0 = deg[base + 0];
    if (base + 1 < N) v1 = deg[base + 1];
    if (base + 2 < N) v2 = deg[base + 2];
  }
  const int tsum = v0 + v1 + v2 + v3;
  __shared__ int s[256];
  s[t] = tsum;
  __syncthreads();
#pragma unroll
  for (int d = 1; d < 256; d <<= 1) {
    int u = (t >= d) ? s[t - d] : 0;
    __syncthreads();
    s[t] += u;
    __syncthreads();
  }
  int exc = s[t] - tsum + boff[blockIdx.x];
  const int o1 = exc + v0, o2 = o1 + v1, o3 = o2 + v2;
  if (base + 0 < N) off[base + 0] = exc;
  if (base + 1 < N) off[base + 1] = o1;
  if (base + 2 < N) off[base + 2] = o2;
  if (base + 3 < N) off[base + 3] = o3;
}

// ---------------- K4: scatter payloads (pos = off[dst] + rank, no atomics) ----------------
__global__ void scatter_pos(const int* __restrict__ esrc, const int* __restrict__ edst,
                            const int* __restrict__ etype, const float* __restrict__ att,
                            const int* __restrict__ off, const int* __restrict__ rank,
                            int2* __restrict__ payload, int E) {
  const int e = (blockIdx.x * 256 + threadIdx.x) * 4;
  if (e + 3 < E) {
    int4 s  = *(const int4*)(esrc + e);
    int4 d  = *(const int4*)(edst + e);
    int4 ty = *(const int4*)(etype + e);
    float4 a = *(const float4*)(att + e);
    int4 rk = *(const int4*)(rank + e);
    payload[off[d.x] + rk.x] = make_int2(s.x | (ty.x << 24), __float_as_int(a.x));
    payload[off[d.y] + rk.y] = make_int2(s.y | (ty.y << 24), __float_as_int(a.y));
    payload[off[d.z] + rk.z] = make_int2(s.z | (ty.z << 24), __float_as_int(a.z));
    payload[off[d.w] + rk.w] = make_int2(s.w | (ty.w << 24), __float_as_int(a.w));
  } else {
    for (int i = e; i < E; ++i)
      payload[off[edst[i]] + rank[i]] =
          make_int2(esrc[i] | (etype[i] << 24), __float_as_int(att[i]));
  }
}

// ---------------- K5: node gather (tiled proj layout) ----------------
__global__ __launch_bounds__(256, 8) void node_gather(const int* __restrict__ off,
                                                      const int2* __restrict__ payload,
                                                      const ushort_t* __restrict__ proj,
                                                      const float* __restrict__ hbias,
                                                      float* __restrict__ out, int N) {
  const int n = (blockIdx.x * 256 + threadIdx.x) >> 6;
  if (n >= N) return;
  const int lane = threadIdx.x & 63;
  const int sub = lane >> 4;
  const int q = lane & 15;
  const int ac0 = 16 * (q & 3) + 4 * (q >> 2);   // actual col base for chunk q

  const int s0 = off[n], s1 = off[n + 1];
  float4 acc = make_float4(0.f, 0.f, 0.f, 0.f);
  float sa = 0.f;
  for (int e = s0 + sub; e < s1; e += 4) {
    const int2 pe = payload[e];
    const float a = __int_as_float(pe.y);
    const int src = pe.x & 0x00FFFFFF;
    const int r = ((unsigned)pe.x) >> 24;
    const ushort4 p = *(const ushort4*)(proj + ((size_t)r * N + src) * D + q * 4);
    acc.x = fmaf(a, bf2f(p.x), acc.x);
    acc.y = fmaf(a, bf2f(p.y), acc.y);
    acc.z = fmaf(a, bf2f(p.z), acc.z);
    acc.w = fmaf(a, bf2f(p.w), acc.w);
    sa += a;
  }
#pragma unroll
  for (int m = 16; m < 64; m <<= 1) {
    acc.x += __shfl_xor(acc.x, m);
    acc.y += __shfl_xor(acc.y, m);
    acc.z += __shfl_xor(acc.z, m);
    acc.w += __shfl_xor(acc.w, m);
    sa += __shfl_xor(sa, m);
  }
  if (sub == 0) {
    const float4 hb = *(const float4*)(hbias + ac0);
    float* op = out + (size_t)n * D + ac0;
    float4 cur = *(float4*)op;      // self-loop already there (canonical layout)
    cur.x += acc.x + sa * hb.x;
    cur.y += acc.y + sa * hb.y;
    cur.z += acc.z + sa * hb.z;
    cur.w += acc.w + sa * hb.w;
    *(float4*)op = cur;
  }
}

// ---------------- fallback path (small ws): fp32 tile GEMM + atomic scatter ----------------
__global__ __launch_bounds__(256, 3) void proj_single(const float* __restrict__ feat,
                                                      const float* __restrict__ W,
                                                      float* __restrict__ outp, int N) {
  __shared__ float sW[64 * 64];
  __shared__ float sF[64 * 132];
  const int t = threadIdx.x;
  const int tileBase = blockIdx.x * 128;

  {
    const float4* Wv = (const float4*)W;
    float4* sWv = (float4*)sW;
    for (int k = t; k < 1024; k += 256) sWv[k] = Wv[k];
  }
  {
    const int row = t >> 1, half = t & 1;
    const int gr = tileBase + row;
    if (gr < N) {
      const float4* src = (const float4*)(feat + (size_t)gr * D + half * 32);
#pragma unroll
      for (int k = 0; k < 8; ++k) {
        float4 v = src[k];
        int i0 = half * 32 + k * 4;
        sF[(i0 + 0) * 132 + row] = v.x;
        sF[(i0 + 1) * 132 + row] = v.y;
        sF[(i0 + 2) * 132 + row] = v.z;
        sF[(i0 + 3) * 132 + row] = v.w;
      }
    } else {
#pragma unroll
      for (int k = 0; k < 8; ++k) {
        int i0 = half * 32 + k * 4;
        sF[(i0 + 0) * 132 + row] = 0.f;
        sF[(i0 + 1) * 132 + row] = 0.f;
        sF[(i0 + 2) * 132 + row] = 0.f;
        sF[(i0 + 3) * 132 + row] = 0.f;
      }
    }
  }
  __syncthreads();

  const int c0 = (t & 15) * 4;
  const int r0 = (t >> 4) * 8;
  float4 acc[8];
#pragma unroll
  for (int rr = 0; rr < 8; ++rr) acc[rr] = make_float4(0.f, 0.f, 0.f, 0.f);

#pragma unroll 8
  for (int i = 0; i < 64; ++i) {
    float4 w  = *(const float4*)&sW[i * 64 + c0];
    float4 a0 = *(const float4*)&sF[i * 132 + r0];
    float4 a1 = *(const float4*)&sF[i * 132 + r0 + 4];
    fma4(acc[0], a0.x, w); fma4(acc[1], a0.y, w);
    fma4(acc[2], a0.z, w); fma4(acc[3], a0.w, w);
    fma4(acc[4], a1.x, w); fma4(acc[5], a1.y, w);
    fma4(acc[6], a1.z, w); fma4(acc[7], a1.w, w);
  }

#pragma unroll
  for (int rr = 0; rr < 8; ++rr) {
    int gn = tileBase + r0 + rr;
    if (gn < N) *(float4*)(outp + (size_t)gn * D + c0) = acc[rr];
  }
}

__global__ __launch_bounds__(256, 8) void edge_scatter(const int* __restrict__ esrc,
                                                       const int* __restrict__ edst,
                                                       const int* __restrict__ etype,
                                                       const float* __restrict__ att,
                                                       const float* __restrict__ proj,
                                                       const float* __restrict__ hbias,
                                                       float* __restrict__ out,
                                                       int E, int N, int relFilter) {
  const int t = blockIdx.x * 256 + threadIdx.x;
  const int wave = t >> 6;
  const int lane = threadIdx.x & 63;
  const int sub = lane >> 4;
  const int q = lane & 15;
  const long e = (long)wave * 4 + sub;
  if (e >= E) return;
  const int r = etype[e];
  if (relFilter >= 0 && r != relFilter) return;
  const int s = esrc[e];
  const int dn = edst[e];
  const float a = att[e];
  const size_t base = (relFilter >= 0) ? (size_t)s * D : ((size_t)r * N + s) * D;
  const float4 hb = ((const float4*)hbias)[q];
  const float4 p = *(const float4*)(proj + base + q * 4);
  float* op = out + (size_t)dn * D + q * 4;
  unsafeAtomicAdd(op + 0, (p.x + hb.x) * a);
  unsafeAtomicAdd(op + 1, (p.y + hb.y) * a);
  unsafeAtomicAdd(op + 2, (p.z + hb.z) * a);
  unsafeAtomicAdd(op + 3, (p.w + hb.w) * a);
}

extern "C" void kernel_launch(void* const* d_in, const int* in_sizes, int n_in,
                              void* d_out, int out_size, void* d_ws, size_t ws_size,
                              hipStream_t stream) {
  const float* feat   = (const float*)d_in[0];
  const int* esrc     = (const int*)d_in[1];
  const int* edst     = (const int*)d_in[2];
  const int* etype    = (const int*)d_in[3];
  const float* att    = (const float*)d_in[4];
  const float* weight = (const float*)d_in[5];
  const float* hbias  = (const float*)d_in[6];
  const float* loopw  = (const float*)d_in[7];
  float* out = (float*)d_out;

  const int N = in_sizes[0] / D;          // 50000
  const int E = in_sizes[1];              // 800000
  const int R = in_sizes[5] / (D * D);    // 8

  const int Npad = (N + 3) & ~3;
  const int nb = (N + 1023) / 1024;

  // Fast-path workspace layout: Wt | proj(bf16) | deg | off | bsum | rank | payload
  const size_t wtBytes   = (size_t)(R + 1) * D * D * 2;
  const size_t projBytes = (size_t)R * N * D * 2;
  const size_t intCount  = (size_t)Npad + (size_t)(N + 1) + (size_t)nb + (size_t)E;
  const size_t payOff    = (wtBytes + projBytes + intCount * 4 + 7) & ~(size_t)7;
  const size_t needSorted = payOff + (size_t)E * 8;

  const int PB = (N + 63) / 64;                       // proj blocks (64 nodes each)
  const int HB = ((E + 1) / 2 + 255) / 256;           // hist blocks (512 edges each)
  const int equadBlocks = ((E + 3) / 4 + 255) / 256;

  if (ws_size >= needSorted) {
    ushort_t* Wt   = (ushort_t*)d_ws;
    ushort_t* proj = (ushort_t*)((char*)d_ws + wtBytes);
    int* deg    = (int*)((char*)d_ws + wtBytes + projBytes);  // Npad ints
    int* off    = deg + Npad;                                 // N+1
    int* bsum   = off + (N + 1);                              // nb (doubles as boff)
    int* rank   = bsum + nb;                                  // E
    int2* payload = (int2*)((char*)d_ws + payOff);            // E

    prep<<<(R + 1) + (N + 255) / 256, 256, 0, stream>>>(weight, loopw, Wt, deg, R, N);
    proj_hist<<<PB + HB, 256, 0, stream>>>(feat, Wt, proj, out, edst, deg, rank,
                                           N, E, R, PB);
    scan_partial<<<nb, 256, 0, stream>>>(deg, bsum, N);
    scan_bsum<<<1, 256, 0, stream>>>(bsum, bsum, off, nb, N);
    scan_apply<<<nb, 256, 0, stream>>>(deg, bsum, off, N);
    scatter_pos<<<equadBlocks, 256, 0, stream>>>(esrc, edst, etype, att, off, rank,
                                                 payload, E);
    node_gather<<<(N + 3) / 4, 256, 0, stream>>>(off, payload, proj, hbias, out, N);
  } else {
    // Minimal-scratch fallback: needs N*D floats.
    const int tilesN = (N + 127) / 128;
    const int eblocks16 = (E + 15) / 16;
    proj_single<<<tilesN, 256, 0, stream>>>(feat, loopw, out, N);
    for (int r = 0; r < R; ++r) {
      proj_single<<<tilesN, 256, 0, stream>>>(feat, weight + (size_t)r * D * D,
                                              (float*)d_ws, N);
      edge_scatter<<<eblocks16, 256, 0, stream>>>(esrc, edst, etype, att, (float*)d_ws,
                                                  hbias, out, E, N, r);
    }
  }
}